// Round 1
// baseline (11.594 us; speedup 1.0000x reference)
//
#include <hip/hip_runtime.h>

#define NT    2048
#define D     16
#define NSEG  32
#define NPAIR 120          // 16*15/2
#define NOUTC 136          // D + NPAIR
#define CHUNK 64           // timesteps staged per LDS tile

__global__ __launch_bounds__(128) void logsig_kernel(
    const float* __restrict__ inp,     // [B, NT, D]
    const int*   __restrict__ length,  // [G]
    float*       __restrict__ out,     // [B, NSEG, NOUTC]
    int batch_size)
{
    const int blk = blockIdx.x;
    const int b   = blk / NSEG;
    const int s   = blk % NSEG;
    const int g   = b / batch_size;
    const int tid = threadIdx.x;

    // --- segment boundaries: tv = round(1 + (L-1)*k/32) - 1, bit-match numpy RNE ---
    const float Lm1 = __fadd_rn((float)length[g], -1.0f);
    const float f0  = (float)s       * (1.0f / 32.0f);   // exact (pow2 divisor)
    const float f1  = (float)(s + 1) * (1.0f / 32.0f);
    const int t0 = (int)rintf(__fadd_rn(1.0f, __fmul_rn(Lm1, f0))) - 1;
    const int t1 = (int)rintf(__fadd_rn(1.0f, __fmul_rn(Lm1, f1))) - 1;

    const float* xrow = inp + (size_t)b * NT * D;

    __shared__ float4 xs4[(CHUNK + 1) * (D / 4)];
    float* xs = (float*)xs4;
    __shared__ float xa_s[D], xe_s[D];

    // pair (pi < pj) for this thread, row-major triu order
    int pi, pj;
    {
        int p = tid, i = 0;
        while (i < D - 1 && p >= (D - 1 - i)) { p -= (D - 1 - i); ++i; }
        pi = i; pj = i + 1 + p;
    }

    // endpoint values for lvl1 / corr
    if (tid < D) {
        xa_s[tid] = xrow[(size_t)t0 * D + tid];
        xe_s[tid] = xrow[(size_t)t1 * D + tid];
    }
    __syncthreads();

    // --- accumulate antisymmetric area over the segment ---
    float acc = 0.0f;
    for (int tc = t0; tc < t1; tc += CHUNK) {
        const int len  = min(CHUNK, t1 - tc);       // steps this tile
        const int nvec = (len + 1) * (D / 4);       // float4s to stage
        const float4* src = (const float4*)(xrow + (size_t)tc * D);
        __syncthreads();                            // xs reuse guard
        for (int v = tid; v < nvec; v += 128)
            xs4[v] = src[v];
        __syncthreads();
        if (tid < NPAIR) {
            float xi = xs[pi];
            float xj = xs[pj];
            for (int t = 0; t < len; ++t) {
                const float xi2 = xs[(t + 1) * D + pi];
                const float xj2 = xs[(t + 1) * D + pj];
                acc = fmaf(xi,  xj2 - xj, acc);     // + x_i * dx_j
                acc = fmaf(-xj, xi2 - xi, acc);     // - x_j * dx_i
                xi = xi2; xj = xj2;
            }
        }
    }

    // --- epilogue ---
    const size_t obase = ((size_t)b * NSEG + s) * NOUTC;
    if (tid < D) {
        out[obase + tid] = xe_s[tid] - xa_s[tid];   // lvl1
    }
    if (tid < NPAIR) {
        const float xai = xa_s[pi], xaj = xa_s[pj];
        const float l1i = xe_s[pi] - xai;
        const float l1j = xe_s[pj] - xaj;
        const float corr = xai * l1j - xaj * l1i;
        out[obase + D + tid] = 0.5f * (acc - corr); // lvl2
    }
}

extern "C" void kernel_launch(void* const* d_in, const int* in_sizes, int n_in,
                              void* d_out, int out_size, void* d_ws, size_t ws_size,
                              hipStream_t stream)
{
    const float* inp    = (const float*)d_in[0];
    const int*   length = (const int*)d_in[1];
    float*       out    = (float*)d_out;

    const int B  = in_sizes[0] / (NT * D);   // 128
    const int G  = in_sizes[1];              // 8
    const int bs = B / G;                    // 16

    const int grid = B * NSEG;               // 4096 blocks
    logsig_kernel<<<grid, 128, 0, stream>>>(inp, length, out, bs);
}

// Round 2
// 9.929 us; speedup vs baseline: 1.1677x; 1.1677x over previous
//
#include <hip/hip_runtime.h>

#define NT    2048
#define D     16
#define NSEG  32
#define NOUTC 136

typedef __attribute__((ext_vector_type(8))) short bf16x8;
typedef __attribute__((ext_vector_type(4))) float f32x4;

__global__ __launch_bounds__(64) void logsig_kernel(
    const float* __restrict__ inp,     // [B, NT, D]
    const int*   __restrict__ length,  // [G]
    float*       __restrict__ out,     // [B, NSEG, NOUTC]
    int batch_size)
{
    const int blk  = blockIdx.x;
    const int b    = blk / NSEG;
    const int s    = blk % NSEG;
    const int g    = b / batch_size;
    const int lane = threadIdx.x;

    __shared__ float xT[D * 68];    // [ch][t], stride 68 floats (272B = 17x16B, b128-aligned rows)
    __shared__ float Cs[16 * 17];   // C transpose-exchange scratch

    // segment boundaries: tv = round(1 + (L-1)*k/32) - 1, bit-match numpy RNE
    const float Lm1 = __fadd_rn((float)length[g], -1.0f);
    const int t0 = (int)rintf(__fadd_rn(1.0f, __fmul_rn(Lm1, (float)s       * (1.0f/32.0f)))) - 1;
    const int t1 = (int)rintf(__fadd_rn(1.0f, __fmul_rn(Lm1, (float)(s + 1) * (1.0f/32.0f)))) - 1;
    const int n  = t1 - t0;                 // steps in segment, 7..64

    const float* xrow = inp + (size_t)b * NT * D;
    const float4* src = (const float4*)(xrow + (size_t)t0 * D);

    // --- stage segment rows t0..t1 transposed into LDS ---
    const int nvec = (n + 1) * 4;           // float4s (<= 260)
    for (int v = lane; v < nvec; v += 64) {
        const float4 q = src[v];
        const int t  = v >> 2;
        const int c4 = (v & 3) << 2;
        xT[(c4 + 0) * 68 + t] = q.x;
        xT[(c4 + 1) * 68 + t] = q.y;
        xT[(c4 + 2) * 68 + t] = q.z;
        xT[(c4 + 3) * 68 + t] = q.w;
    }
    __syncthreads();

    // --- MFMA: M(i,j) = sum_k x_i(k) * dx_j(k), via bf16 hi/lo split ---
    const int ch = lane & 15;   // A row i-channel == B col j-channel for this lane
    const int tb = lane >> 4;   // k-block: lane supplies k = kb + 8*tb + e
    const float* base = &xT[ch * 68];

    f32x4 acc = {0.f, 0.f, 0.f, 0.f};
    const int nchunks = (n > 32) ? 2 : 1;

    for (int c = 0; c < nchunks; ++c) {
        const int kb = c * 32 + 8 * tb;     // first k index this lane supplies
        const f32x4 q0 = *(const f32x4*)(base + kb);
        const f32x4 q1 = *(const f32x4*)(base + kb + 4);
        const float x9 = base[kb + 8];
        float xv[9] = {q0[0], q0[1], q0[2], q0[3], q1[0], q1[1], q1[2], q1[3], x9};

        bf16x8 Ah, Al, Bh, Bl;
        #pragma unroll
        for (int e = 0; e < 8; ++e) {
            const int idx = kb + e;
            const float xm  = (idx <= n) ? xv[e] : 0.0f;              // mask garbage beyond staged range
            const float dxm = (idx <  n) ? (xv[e + 1] - xv[e]) : 0.0f; // dx = 0 past segment end
            const unsigned bx = __float_as_uint(xm);
            Ah[e] = (short)(bx >> 16);                                 // bf16 truncation (hi)
            const float lx = xm - __uint_as_float(bx & 0xFFFF0000u);   // exact remainder
            Al[e] = (short)(__float_as_uint(lx) >> 16);
            const unsigned bd = __float_as_uint(dxm);
            Bh[e] = (short)(bd >> 16);
            const float ld = dxm - __uint_as_float(bd & 0xFFFF0000u);
            Bl[e] = (short)(__float_as_uint(ld) >> 16);
        }
        acc = __builtin_amdgcn_mfma_f32_16x16x32_bf16(Ah, Bh, acc, 0, 0, 0);
        acc = __builtin_amdgcn_mfma_f32_16x16x32_bf16(Ah, Bl, acc, 0, 0, 0);
        acc = __builtin_amdgcn_mfma_f32_16x16x32_bf16(Al, Bh, acc, 0, 0, 0);
    }

    // acc[e] = M(i = 4*tb + e, j = ch)   [C/D layout: col = lane&15, row = 4*(lane>>4)+reg]
    // need M(j, i): exchange through LDS
    #pragma unroll
    for (int e = 0; e < 4; ++e)
        Cs[(4 * tb + e) * 17 + ch] = acc[e];
    __syncthreads();

    const float xa_j = base[0];
    const float xe_j = base[n];
    const size_t obase = ((size_t)b * NSEG + s) * NOUTC;

    if (tb == 0) {
        out[obase + ch] = xe_j - xa_j;      // lvl1
    }
    #pragma unroll
    for (int e = 0; e < 4; ++e) {
        const int i = 4 * tb + e;
        const int j = ch;
        if (i < j) {
            const float Mt   = Cs[j * 17 + i];           // M(j, i)
            const float xa_i = xT[i * 68 + 0];
            const float xe_i = xT[i * 68 + n];
            const float corr = xa_i * (xe_j - xa_j) - xa_j * (xe_i - xa_i);
            const int oidx   = 15 * i - (i * (i - 1)) / 2 + (j - i - 1);
            out[obase + D + oidx] = 0.5f * (acc[e] - Mt - corr);
        }
    }
}

extern "C" void kernel_launch(void* const* d_in, const int* in_sizes, int n_in,
                              void* d_out, int out_size, void* d_ws, size_t ws_size,
                              hipStream_t stream)
{
    const float* inp    = (const float*)d_in[0];
    const int*   length = (const int*)d_in[1];
    float*       out    = (float*)d_out;

    const int B  = in_sizes[0] / (NT * D);   // 128
    const int G  = in_sizes[1];              // 8
    const int bs = B / G;                    // 16

    const int grid = B * NSEG;               // 4096 blocks, 1 wave each
    logsig_kernel<<<grid, 64, 0, stream>>>(inp, length, out, bs);
}